// Round 11
// baseline (182.837 us; speedup 1.0000x reference)
//
#include <hip/hip_runtime.h>
#include <hip/hip_bf16.h>
#include <math.h>

#define B_  4
#define T_  1024
#define C_  768
#define H_  12
#define HD_ 64
#define M_  (B_*T_)     // 4096 rows
#define C3_ (3*C_)      // 2304
#define C4_ (4*C_)      // 3072

typedef __bf16 bf16;
typedef bf16  bf16x2 __attribute__((ext_vector_type(2)));
typedef bf16  bf16x8 __attribute__((ext_vector_type(8)));
typedef float f32x4  __attribute__((ext_vector_type(4)));

__device__ __forceinline__ f32x4 mfma16(bf16x8 a, bf16x8 b, f32x4 c) {
    return __builtin_amdgcn_mfma_f32_16x16x32_bf16(a, b, c, 0, 0, 0);
}

#define GLOAD_LDS16(g, l)                                                     \
    __builtin_amdgcn_global_load_lds(                                         \
        (const __attribute__((address_space(1))) void*)(g),                   \
        (__attribute__((address_space(3))) void*)(l), 16, 0, 0)

// ---------------------------------------------------------------------------
// Merged transpose+cast for all 4 weights: fp32 [K,N] -> bf16 [N,K].
// ---------------------------------------------------------------------------
__global__ void tcast_all_kernel(const float* __restrict__ Wqkv,
                                 const float* __restrict__ Wo,
                                 const float* __restrict__ Wfc,
                                 const float* __restrict__ Wproj,
                                 bf16* __restrict__ WqkvT, bf16* __restrict__ WoT,
                                 bf16* __restrict__ WfcT, bf16* __restrict__ WprojT) {
    __shared__ float tile[32][33];
    const int id = blockIdx.x;
    const float* in; bf16* out; int K, N, local;
    if (id < 1728)      { in = Wqkv;  out = WqkvT;  K = 768;  N = 2304; local = id; }
    else if (id < 2304) { in = Wo;    out = WoT;    K = 768;  N = 768;  local = id - 1728; }
    else if (id < 4608) { in = Wfc;   out = WfcT;   K = 768;  N = 3072; local = id - 2304; }
    else                { in = Wproj; out = WprojT; K = 3072; N = 768;  local = id - 4608; }
    const int tn = N >> 5;
    const int n0 = (local % tn) * 32, k0 = (local / tn) * 32;
    const int tx = threadIdx.x, ty = threadIdx.y;  // 32 x 8
#pragma unroll
    for (int i = 0; i < 32; i += 8)
        tile[ty + i][tx] = in[(size_t)(k0 + ty + i) * N + n0 + tx];
    __syncthreads();
#pragma unroll
    for (int i = 0; i < 32; i += 8)
        out[(size_t)(n0 + ty + i) * K + k0 + tx] = (bf16)tile[tx][ty + i];
}

// ---------------------------------------------------------------------------
// LayerNorm: fp32 in [rows, 768] -> bf16 out. One block (256 thr) per row.
// ---------------------------------------------------------------------------
__device__ __forceinline__ float block_sum256(float v, float* red, int tid) {
#pragma unroll
    for (int m = 32; m >= 1; m >>= 1) v += __shfl_xor(v, m, 64);
    if ((tid & 63) == 0) red[tid >> 6] = v;
    __syncthreads();
    v = red[0] + red[1] + red[2] + red[3];
    __syncthreads();
    return v;
}

__global__ __launch_bounds__(256) void ln_kernel(const float* __restrict__ in,
                                                 const float* __restrict__ scale,
                                                 const float* __restrict__ bias,
                                                 bf16* __restrict__ out) {
    __shared__ float red[4];
    int row = blockIdx.x, tid = threadIdx.x;
    const float* p = in + (size_t)row * C_;
    float v0 = p[tid], v1 = p[tid + 256], v2 = p[tid + 512];
    float mu = block_sum256(v0 + v1 + v2, red, tid) * (1.0f / C_);
    float d0 = v0 - mu, d1 = v1 - mu, d2 = v2 - mu;
    float var = block_sum256(d0 * d0 + d1 * d1 + d2 * d2, red, tid) * (1.0f / C_);
    float rstd = rsqrtf(var + 1e-5f);
    bf16* o = out + (size_t)row * C_;
    o[tid]       = (bf16)(d0 * rstd * scale[tid]       + bias[tid]);
    o[tid + 256] = (bf16)(d1 * rstd * scale[tid + 256] + bias[tid + 256]);
    o[tid + 512] = (bf16)(d2 * rstd * scale[tid + 512] + bias[tid + 512]);
}

// ---------------------------------------------------------------------------
// GEMM: C[M,N] = A[M,K] * BT[N,K]^T (+epilogue). BM = MT*32, BN=128, BK=32,
// 4 waves (2x2), 3 LDS buffers, depth-2 prefetch, counted vmcnt,
// swizzle c^((row>>1)&3) (0 conflicts). Round-11: SINGLE barrier per K-step —
// stage issue moved AFTER the barrier, so the buffer-reuse race barrier#2
// guarded against cannot occur (overwrite of buf[t%3] is issued at iter t+1
// after barrier(t+1); all waves' reads of buf[t%3] complete before reaching
// barrier(t+1) via the MFMA data dependency).
// ---------------------------------------------------------------------------
enum { EPI_BF16 = 0, EPI_RES_F32 = 1, EPI_GELU_BF16 = 2, EPI_PARTIAL = 3 };

template <int EPI, int MT>
__global__ __launch_bounds__(256) void gemm_kernel(
    const bf16* __restrict__ A, const bf16* __restrict__ BT,
    const float* __restrict__ bias, const float* __restrict__ res,
    void* __restrict__ outv, int N, int Ktot, int nx) {
    constexpr int BM = MT * 32;
    constexpr int LPS = (MT == 4) ? 4 : 3;  // loads per stage
    __shared__ bf16 Al[3][BM * 32];
    __shared__ bf16 Bl[3][128 * 32];
    const int tid = threadIdx.x;
    const int l = tid & 63, w = tid >> 6;
    const int wm = w >> 1, wn = w & 1;
    // bijective XCD-chunked swizzle (gridDim.x divisible by 8)
    const int cpx = gridDim.x >> 3;
    const int wg = (blockIdx.x & 7) * cpx + (blockIdx.x >> 3);
    const int bm = (wg / nx) * BM, bn = (wg % nx) * 128;
    const int Kper = Ktot / gridDim.y;
    const int k0 = blockIdx.y * Kper;
    const int lr = l & 15, lh = l >> 4;

    // staging: LDS chunk (row, c) holds global k-chunk c ^ ((row>>1)&3);
    const int srow = tid >> 2;
    const int scol = ((tid & 3) ^ ((srow >> 1) & 3)) * 8;
    const bf16* gA = A + (size_t)(bm + srow) * Ktot + k0 + scol;
    const bf16* gB = BT + (size_t)(bn + srow) * Ktot + k0 + scol;

// koff = K offset in ELEMENTS within this block's K-slice.
#define GEMM_STAGE(buf, koff)                                                  \
    {                                                                          \
        GLOAD_LDS16(gA + (koff), &Al[buf][tid * 8]);                           \
        if (MT == 4)                                                           \
            GLOAD_LDS16(gA + (size_t)64 * Ktot + (koff),                       \
                        &Al[buf][(tid + 256) * 8]);                            \
        GLOAD_LDS16(gB + (koff), &Bl[buf][tid * 8]);                           \
        GLOAD_LDS16(gB + (size_t)64 * Ktot + (koff),                           \
                    &Bl[buf][(tid + 256) * 8]);                                \
    }

    // read-side swizzled chunk offset (elements) within a 32-elem row
    const int rdoff = (lh ^ ((lr >> 1) & 3)) * 8;

    f32x4 acc[MT][4] = {};
    const int nk = Kper >> 5;

    GEMM_STAGE(0, 0);
    GEMM_STAGE(1, 32);

    int cur = 0, sb = 2;
    for (int t = 0; t < nk; ++t) {
        // tile t landed (t+1's LPS loads may remain in flight)
        if (t + 1 < nk) {
            if (MT == 4) asm volatile("s_waitcnt vmcnt(4)" ::: "memory");
            else         asm volatile("s_waitcnt vmcnt(3)" ::: "memory");
        } else {
            asm volatile("s_waitcnt vmcnt(0)" ::: "memory");
        }
        __builtin_amdgcn_s_barrier();  // the ONLY barrier per K-step

        if (t + 2 < nk) GEMM_STAGE(sb, (t + 2) * 32);  // issue after barrier

        bf16x8 af[MT], bfr[4];
#pragma unroll
        for (int mt = 0; mt < MT; ++mt)
            af[mt] = *(const bf16x8*)(&Al[cur][(wm * (MT * 16) + mt * 16 + lr) * 32 + rdoff]);
#pragma unroll
        for (int nt = 0; nt < 4; ++nt)
            bfr[nt] = *(const bf16x8*)(&Bl[cur][(wn * 64 + nt * 16 + lr) * 32 + rdoff]);

#pragma unroll
        for (int mt = 0; mt < MT; ++mt)
#pragma unroll
            for (int nt = 0; nt < 4; ++nt)
                acc[mt][nt] = mfma16(af[mt], bfr[nt], acc[mt][nt]);

        cur = (cur == 2) ? 0 : cur + 1;
        sb = (sb == 2) ? 0 : sb + 1;
    }
#undef GEMM_STAGE

#pragma unroll
    for (int mt = 0; mt < MT; ++mt) {
#pragma unroll
        for (int nt = 0; nt < 4; ++nt) {
#pragma unroll
            for (int r = 0; r < 4; ++r) {
                int row = bm + wm * (MT * 16) + mt * 16 + lh * 4 + r;
                int col = bn + wn * 64 + nt * 16 + lr;
                if (EPI == EPI_PARTIAL) {
                    ((float*)outv)[(size_t)blockIdx.y * M_ * N +
                                   (size_t)row * N + col] = acc[mt][nt][r];
                } else {
                    float v = acc[mt][nt][r] + bias[col];
                    if (EPI == EPI_RES_F32) {
                        ((float*)outv)[(size_t)row * N + col] =
                            v + res[(size_t)row * N + col];
                    } else if (EPI == EPI_GELU_BF16) {
                        // faithful: tanh(z), z = sqrt(2/pi)*0.044715*x^4
                        // g = v - v/(e^{2z}+1); z>=0, inf-safe.
                        float x4 = v * v * v * v;
                        float e = __expf(0.07135494f * x4);  // e^{2z}
                        float g = v - v / (e + 1.0f);
                        ((bf16*)outv)[(size_t)row * N + col] = (bf16)g;
                    } else {
                        ((bf16*)outv)[(size_t)row * N + col] = (bf16)v;
                    }
                }
            }
        }
    }
}

// ---------------------------------------------------------------------------
// Split-K=2 reduce: out = part0 + part1 + bias + res   (fp32, float4)
// ---------------------------------------------------------------------------
__global__ __launch_bounds__(256) void reduce2_kernel(const float* __restrict__ part,
                                                      const float* __restrict__ bias,
                                                      const float* __restrict__ res,
                                                      float* __restrict__ out) {
    const size_t MN = (size_t)M_ * C_;
    size_t i = ((size_t)blockIdx.x * 256 + threadIdx.x) * 4;
    if (i >= MN) return;
    f32x4 a = *(const f32x4*)(part + i);
    f32x4 b = *(const f32x4*)(part + MN + i);
    f32x4 r = *(const f32x4*)(res + i);
    f32x4 bi = *(const f32x4*)(bias + (int)(i % C_));
    *(f32x4*)(out + i) = a + b + r + bi;
}

// ---------------------------------------------------------------------------
// V pre-transpose: qkv V-part [t][d] per head -> vt[(b*H+h)][d=64][T=1024]
// ---------------------------------------------------------------------------
__global__ __launch_bounds__(256) void vtrans_kernel(const bf16* __restrict__ qkv,
                                                     bf16* __restrict__ vt) {
    __shared__ bf16 tl[64 * 64];
    const int tid = threadIdx.x;
    const int t0 = blockIdx.x * 64;
    const int hv = blockIdx.y;          // b*H + h
    const int b = hv / H_, h = hv % H_;
    const int src0 = h * 192 + 128;
#pragma unroll
    for (int c = 0; c < 2; ++c) {
        int i = tid + c * 256;
        int row = i >> 3, seg = i & 7;  // row = t-within-tile
        bf16x8 v = *(const bf16x8*)(qkv + (size_t)(b * T_ + t0 + row) * C3_ +
                                    src0 + seg * 8);
        *(bf16x8*)(tl + row * 64 + ((seg ^ (row & 7)) * 8)) = v;
    }
    __syncthreads();
#pragma unroll
    for (int c = 0; c < 2; ++c) {
        int i = tid + c * 256;
        int d = i >> 3, ts = i & 7;
        bf16x8 o;
#pragma unroll
        for (int j = 0; j < 8; ++j)
            o[j] = tl[(ts * 8 + j) * 64 + (d ^ (j * 8))];
        *(bf16x8*)(vt + (size_t)(hv * 64 + d) * T_ + t0 + ts * 8) = o;
    }
}

// ---------------------------------------------------------------------------
// Causal flash attention, swapped-QK^T. Depth-2 prefetch (3 buffers),
// SINGLE barrier per kc (same argument as GEMM: stage issued after barrier;
// Pl is per-wave). Grid 768 flat, XCD-grouped per (b,h).
// ---------------------------------------------------------------------------
__global__ __launch_bounds__(256) void attn_kernel(const bf16* __restrict__ qkv,
                                                   const bf16* __restrict__ vt,
                                                   bf16* __restrict__ y) {
    const int flat = blockIdx.x;
    const int g = (flat & 7) * 6 + (flat >> 3) / 16;  // 0..47 = b*H+h
    const int qt = (flat >> 3) & 15;
    const int h = g % H_, b = g / H_, hv = g;

    const int tid = threadIdx.x, l = tid & 63, w = tid >> 6;
    const int lr = l & 15, lh = l >> 4, d0 = lh * 8;
    const int bc = h * 192;

    __shared__ bf16 Kl[3][64 * 64];
    __shared__ bf16 Vl[3][64 * 64];
    __shared__ bf16 Pl[4][16 * 64];

    const int qg = qt * 64 + w * 16 + lr;
    const bf16* qp = qkv + (size_t)(b * T_ + qg) * C3_ + bc;
    bf16x8 qf0 = *(const bf16x8*)(qp + d0);
    bf16x8 qf1 = *(const bf16x8*)(qp + 32 + d0);

    const int srow = tid >> 3;
    const int ss = (tid & 7) ^ (srow & 7);
    const bf16* k0p = qkv + (size_t)(b * T_ + srow) * C3_ + bc + 64 + ss * 8;
    const bf16* k1p = k0p + (size_t)32 * C3_;
    const bf16* v0p = vt + (size_t)(hv * 64 + srow) * T_ + ss * 8;
    const bf16* v1p = v0p + (size_t)32 * T_;

#define ATTN_STAGE(buf, kc)                                                    \
    {                                                                          \
        GLOAD_LDS16(k0p + (size_t)(kc) * 64 * C3_, &Kl[buf][tid * 8]);         \
        GLOAD_LDS16(v0p + (kc) * 64, &Vl[buf][tid * 8]);                       \
        GLOAD_LDS16(k1p + (size_t)(kc) * 64 * C3_, &Kl[buf][(tid + 256) * 8]); \
        GLOAD_LDS16(v1p + (kc) * 64, &Vl[buf][(tid + 256) * 8]);               \
    }

    f32x4 acc_o[4] = {};
    float m_run = -1e30f, l_run = 0.f;
    const float SCL = 0.125f * 1.44269504089f;  // 1/sqrt(HD) * log2(e)

    ATTN_STAGE(0, 0);
    if (qt >= 1) ATTN_STAGE(1, 1);

    int cur = 0, nxt = 2;
    for (int kc = 0; kc <= qt; ++kc) {
        if (kc + 1 <= qt) {
            asm volatile("s_waitcnt vmcnt(4)" ::: "memory");
        } else {
            asm volatile("s_waitcnt vmcnt(0)" ::: "memory");
        }
        __builtin_amdgcn_s_barrier();  // the ONLY barrier per kc

        if (kc + 2 <= qt) ATTN_STAGE(nxt, kc + 2);  // issue after barrier

        const bf16* Kb = Kl[cur];
        const bf16* Vb = Vl[cur];

        // S^T = K Q^T : lane holds S[k = kc*64+nt*16+lh*4+r][q = qg]
        f32x4 st[4];
#pragma unroll
        for (int nt = 0; nt < 4; ++nt) {
            int R = nt * 16 + lr;
            const bf16* kb = Kb + R * 64;
            bf16x8 k0 = *(const bf16x8*)(kb + (lh ^ (R & 7)) * 8);
            bf16x8 k1 = *(const bf16x8*)(kb + ((4 + lh) ^ (R & 7)) * 8);
            f32x4 a = {};
            a = mfma16(k0, qf0, a);
            st[nt] = mfma16(k1, qf1, a);
        }

        // softmax in log2 domain; lane owns q-row qg, 16 k-values
        const int diag = (kc == qt);
        float p[16], pmax = -1e30f;
#pragma unroll
        for (int nt = 0; nt < 4; ++nt)
#pragma unroll
            for (int r = 0; r < 4; ++r) {
                float v = st[nt][r] * SCL;
                if (diag) {
                    int kg = kc * 64 + nt * 16 + lh * 4 + r;
                    if (kg > qg) v = -1e38f;
                }
                p[nt * 4 + r] = v;
                pmax = fmaxf(pmax, v);
            }
        pmax = fmaxf(pmax, __shfl_xor(pmax, 16, 64));
        pmax = fmaxf(pmax, __shfl_xor(pmax, 32, 64));

        if (!__all(pmax - m_run <= 8.0f)) {  // defer-max (T13), THR=8 (log2)
            float mnew = fmaxf(m_run, pmax);
            float sc = exp2f(m_run - mnew);
            l_run *= sc;
            m_run = mnew;
#pragma unroll
            for (int r = 0; r < 4; ++r) {
                float sq = __shfl(sc, lh * 4 + r, 64);
#pragma unroll
                for (int nt = 0; nt < 4; ++nt) acc_o[nt][r] *= sq;
            }
        }

        float lsum = 0.f;
#pragma unroll
        for (int i = 0; i < 16; ++i) {
            p[i] = exp2f(p[i] - m_run);
            lsum += p[i];
        }
        lsum += __shfl_xor(lsum, 16, 64);
        lsum += __shfl_xor(lsum, 32, 64);
        l_run += lsum;

        // P -> Pl[q_local = lr][k], swizzled rows (per-wave buffer)
        {
            char* pw = (char*)&Pl[w][0];
            int swz = (lr & 7) << 4;
#pragma unroll
            for (int nt = 0; nt < 4; ++nt)
#pragma unroll
                for (int rr = 0; rr < 2; ++rr) {
                    int kk = nt * 16 + lh * 4 + rr * 2;
                    bf16x2 pr = {(bf16)p[nt * 4 + rr * 2],
                                 (bf16)p[nt * 4 + rr * 2 + 1]};
                    *(bf16x2*)(pw + lr * 128 + ((kk * 2) ^ swz)) = pr;
                }
        }

        // PV: a-frag = Pl rows (q_local), b-frag = Vl rows (d)
        {
            const bf16* pb = &Pl[w][0] + lr * 64;
            bf16x8 pa0 = *(const bf16x8*)(pb + (lh ^ (lr & 7)) * 8);
            bf16x8 pa1 = *(const bf16x8*)(pb + ((4 + lh) ^ (lr & 7)) * 8);
#pragma unroll
            for (int nt = 0; nt < 4; ++nt) {
                int R = nt * 16 + lr;
                const bf16* vb = Vb + R * 64;
                bf16x8 v0 = *(const bf16x8*)(vb + (lh ^ (R & 7)) * 8);
                bf16x8 v1 = *(const bf16x8*)(vb + ((4 + lh) ^ (R & 7)) * 8);
                acc_o[nt] = mfma16(pa0, v0, acc_o[nt]);
                acc_o[nt] = mfma16(pa1, v1, acc_o[nt]);
            }
        }

        cur = (cur == 2) ? 0 : cur + 1;
        nxt = (nxt == 2) ? 0 : nxt + 1;
    }

    float rl = 1.0f / l_run;
#pragma unroll
    for (int r = 0; r < 4; ++r) {
        float rq = __shfl(rl, lh * 4 + r, 64);
        int q = qt * 64 + w * 16 + lh * 4 + r;
#pragma unroll
        for (int nt = 0; nt < 4; ++nt)
            y[(size_t)(b * T_ + q) * C_ + h * 64 + nt * 16 + lr] =
                (bf16)(acc_o[nt][r] * rq);
    }
#undef ATTN_STAGE
}

// ---------------------------------------------------------------------------
extern "C" void kernel_launch(void* const* d_in, const int* in_sizes, int n_in,
                              void* d_out, int out_size, void* d_ws, size_t ws_size,
                              hipStream_t stream) {
    (void)in_sizes; (void)n_in; (void)out_size; (void)ws_size;
    const float* x     = (const float*)d_in[0];
    const float* ln1_s = (const float*)d_in[1];
    const float* ln1_b = (const float*)d_in[2];
    const float* Wqkv  = (const float*)d_in[3];
    const float* bqkv  = (const float*)d_in[4];
    const float* Wo    = (const float*)d_in[5];
    const float* bo    = (const float*)d_in[6];
    const float* ln2_s = (const float*)d_in[7];
    const float* ln2_b = (const float*)d_in[8];
    const float* Wfc   = (const float*)d_in[9];
    const float* bfc   = (const float*)d_in[10];
    const float* Wproj = (const float*)d_in[11];
    const float* bproj = (const float*)d_in[12];

    char* ws = (char*)d_ws;
    float* x2     = (float*)(ws);
    bf16*  vtbuf  = (bf16*)(ws);                      // aliases x2 (live: vtrans..attn)
    bf16*  fcbuf  = (bf16*)(ws + 12582912);
    bf16*  WprojT = (bf16*)(ws + 37748736);
    bf16*  lnbuf  = (bf16*)(ws + 42467328);
    float* parts  = (float*)(ws + 42467328);          // aliases lnbuf+qkv (live: proj..reduce)
    bf16*  qkv    = (bf16*)(ws + 48758784);
    bf16*  WqkvT  = (bf16*)(ws + 67633152);
    bf16*  WoT    = (bf16*)(ws + 71172096);
    bf16*  WfcT   = (bf16*)(ws + 72351744);

    tcast_all_kernel<<<dim3(6912), dim3(32, 8), 0, stream>>>(
        Wqkv, Wo, Wfc, Wproj, WqkvT, WoT, WfcT, WprojT);

    ln_kernel<<<M_, 256, 0, stream>>>(x, ln1_s, ln1_b, lnbuf);

    gemm_kernel<EPI_BF16, 4><<<dim3(576, 1), 256, 0, stream>>>(
        lnbuf, WqkvT, bqkv, nullptr, qkv, C3_, C_, 18);

    vtrans_kernel<<<dim3(T_ / 64, B_ * H_), 256, 0, stream>>>(qkv, vtbuf);

    attn_kernel<<<dim3(768), 256, 0, stream>>>(qkv, vtbuf, lnbuf);

    // wo: N=768, K=768 -> MT=2, grid 384 (4 blocks/CU)
    gemm_kernel<EPI_RES_F32, 2><<<dim3(384, 1), 256, 0, stream>>>(
        lnbuf, WoT, bo, x, x2, C_, C_, 6);

    ln_kernel<<<M_, 256, 0, stream>>>(x2, ln2_s, ln2_b, lnbuf);

    // fc: 32 M-tiles x 24 N-tiles = 768 blocks
    gemm_kernel<EPI_GELU_BF16, 4><<<dim3(768, 1), 256, 0, stream>>>(
        lnbuf, WfcT, bfc, nullptr, fcbuf, C4_, C_, 24);

    // proj: MT=4 + split-K=2
    gemm_kernel<EPI_PARTIAL, 4><<<dim3(192, 2), 256, 0, stream>>>(
        fcbuf, WprojT, nullptr, nullptr, parts, C_, C4_, 6);

    reduce2_kernel<<<dim3((M_ * C_) / 1024), 256, 0, stream>>>(parts, bproj, x2,
                                                               (float*)d_out);
}

// Round 12
// 176.413 us; speedup vs baseline: 1.0364x; 1.0364x over previous
//
#include <hip/hip_runtime.h>
#include <hip/hip_bf16.h>
#include <math.h>

#define B_  4
#define T_  1024
#define C_  768
#define H_  12
#define HD_ 64
#define M_  (B_*T_)     // 4096 rows
#define C3_ (3*C_)      // 2304
#define C4_ (4*C_)      // 3072

typedef __bf16 bf16;
typedef bf16  bf16x2 __attribute__((ext_vector_type(2)));
typedef bf16  bf16x8 __attribute__((ext_vector_type(8)));
typedef float f32x4  __attribute__((ext_vector_type(4)));

__device__ __forceinline__ f32x4 mfma16(bf16x8 a, bf16x8 b, f32x4 c) {
    return __builtin_amdgcn_mfma_f32_16x16x32_bf16(a, b, c, 0, 0, 0);
}

#define GLOAD_LDS16(g, l)                                                     \
    __builtin_amdgcn_global_load_lds(                                         \
        (const __attribute__((address_space(1))) void*)(g),                   \
        (__attribute__((address_space(3))) void*)(l), 16, 0, 0)

// ---------------------------------------------------------------------------
// Merged transpose+cast for all 4 weights: fp32 [K,N] -> bf16 [N,K].
// ---------------------------------------------------------------------------
__global__ void tcast_all_kernel(const float* __restrict__ Wqkv,
                                 const float* __restrict__ Wo,
                                 const float* __restrict__ Wfc,
                                 const float* __restrict__ Wproj,
                                 bf16* __restrict__ WqkvT, bf16* __restrict__ WoT,
                                 bf16* __restrict__ WfcT, bf16* __restrict__ WprojT) {
    __shared__ float tile[32][33];
    const int id = blockIdx.x;
    const float* in; bf16* out; int K, N, local;
    if (id < 1728)      { in = Wqkv;  out = WqkvT;  K = 768;  N = 2304; local = id; }
    else if (id < 2304) { in = Wo;    out = WoT;    K = 768;  N = 768;  local = id - 1728; }
    else if (id < 4608) { in = Wfc;   out = WfcT;   K = 768;  N = 3072; local = id - 2304; }
    else                { in = Wproj; out = WprojT; K = 3072; N = 768;  local = id - 4608; }
    const int tn = N >> 5;
    const int n0 = (local % tn) * 32, k0 = (local / tn) * 32;
    const int tx = threadIdx.x, ty = threadIdx.y;  // 32 x 8
#pragma unroll
    for (int i = 0; i < 32; i += 8)
        tile[ty + i][tx] = in[(size_t)(k0 + ty + i) * N + n0 + tx];
    __syncthreads();
#pragma unroll
    for (int i = 0; i < 32; i += 8)
        out[(size_t)(n0 + ty + i) * K + k0 + tx] = (bf16)tile[tx][ty + i];
}

// ---------------------------------------------------------------------------
// LayerNorm: fp32 in [rows, 768] -> bf16 out. One block (256 thr) per row.
// ---------------------------------------------------------------------------
__device__ __forceinline__ float block_sum256(float v, float* red, int tid) {
#pragma unroll
    for (int m = 32; m >= 1; m >>= 1) v += __shfl_xor(v, m, 64);
    if ((tid & 63) == 0) red[tid >> 6] = v;
    __syncthreads();
    v = red[0] + red[1] + red[2] + red[3];
    __syncthreads();
    return v;
}

__global__ __launch_bounds__(256) void ln_kernel(const float* __restrict__ in,
                                                 const float* __restrict__ scale,
                                                 const float* __restrict__ bias,
                                                 bf16* __restrict__ out) {
    __shared__ float red[4];
    int row = blockIdx.x, tid = threadIdx.x;
    const float* p = in + (size_t)row * C_;
    float v0 = p[tid], v1 = p[tid + 256], v2 = p[tid + 512];
    float mu = block_sum256(v0 + v1 + v2, red, tid) * (1.0f / C_);
    float d0 = v0 - mu, d1 = v1 - mu, d2 = v2 - mu;
    float var = block_sum256(d0 * d0 + d1 * d1 + d2 * d2, red, tid) * (1.0f / C_);
    float rstd = rsqrtf(var + 1e-5f);
    bf16* o = out + (size_t)row * C_;
    o[tid]       = (bf16)(d0 * rstd * scale[tid]       + bias[tid]);
    o[tid + 256] = (bf16)(d1 * rstd * scale[tid + 256] + bias[tid + 256]);
    o[tid + 512] = (bf16)(d2 * rstd * scale[tid + 512] + bias[tid + 512]);
}

// ---------------------------------------------------------------------------
// GEMM: C[M,N] = A[M,K] * BT[N,K]^T (+epilogue). BM = MT*32, BN=128, BK=32,
// 4 waves (2x2), 3 LDS buffers, depth-2 prefetch, counted vmcnt, single
// barrier per K-step (stage issued after barrier), swizzle c^((row>>1)&3).
// Converged at these shapes (rounds 4-11): ~490 TF, above m102 ref curve.
// ---------------------------------------------------------------------------
enum { EPI_BF16 = 0, EPI_RES_F32 = 1, EPI_GELU_BF16 = 2, EPI_PARTIAL = 3 };

template <int EPI, int MT>
__global__ __launch_bounds__(256) void gemm_kernel(
    const bf16* __restrict__ A, const bf16* __restrict__ BT,
    const float* __restrict__ bias, const float* __restrict__ res,
    void* __restrict__ outv, int N, int Ktot, int nx) {
    constexpr int BM = MT * 32;
    __shared__ bf16 Al[3][BM * 32];
    __shared__ bf16 Bl[3][128 * 32];
    const int tid = threadIdx.x;
    const int l = tid & 63, w = tid >> 6;
    const int wm = w >> 1, wn = w & 1;
    // bijective XCD-chunked swizzle (gridDim.x divisible by 8)
    const int cpx = gridDim.x >> 3;
    const int wg = (blockIdx.x & 7) * cpx + (blockIdx.x >> 3);
    const int bm = (wg / nx) * BM, bn = (wg % nx) * 128;
    const int Kper = Ktot / gridDim.y;
    const int k0 = blockIdx.y * Kper;
    const int lr = l & 15, lh = l >> 4;

    const int srow = tid >> 2;
    const int scol = ((tid & 3) ^ ((srow >> 1) & 3)) * 8;
    const bf16* gA = A + (size_t)(bm + srow) * Ktot + k0 + scol;
    const bf16* gB = BT + (size_t)(bn + srow) * Ktot + k0 + scol;

#define GEMM_STAGE(buf, koff)                                                  \
    {                                                                          \
        GLOAD_LDS16(gA + (koff), &Al[buf][tid * 8]);                           \
        if (MT == 4)                                                           \
            GLOAD_LDS16(gA + (size_t)64 * Ktot + (koff),                       \
                        &Al[buf][(tid + 256) * 8]);                            \
        GLOAD_LDS16(gB + (koff), &Bl[buf][tid * 8]);                           \
        GLOAD_LDS16(gB + (size_t)64 * Ktot + (koff),                           \
                    &Bl[buf][(tid + 256) * 8]);                                \
    }

    const int rdoff = (lh ^ ((lr >> 1) & 3)) * 8;

    f32x4 acc[MT][4] = {};
    const int nk = Kper >> 5;

    GEMM_STAGE(0, 0);
    GEMM_STAGE(1, 32);

    int cur = 0, sb = 2;
    for (int t = 0; t < nk; ++t) {
        if (t + 1 < nk) {
            if (MT == 4) asm volatile("s_waitcnt vmcnt(4)" ::: "memory");
            else         asm volatile("s_waitcnt vmcnt(3)" ::: "memory");
        } else {
            asm volatile("s_waitcnt vmcnt(0)" ::: "memory");
        }
        __builtin_amdgcn_s_barrier();  // the ONLY barrier per K-step

        if (t + 2 < nk) GEMM_STAGE(sb, (t + 2) * 32);  // issue after barrier

        bf16x8 af[MT], bfr[4];
#pragma unroll
        for (int mt = 0; mt < MT; ++mt)
            af[mt] = *(const bf16x8*)(&Al[cur][(wm * (MT * 16) + mt * 16 + lr) * 32 + rdoff]);
#pragma unroll
        for (int nt = 0; nt < 4; ++nt)
            bfr[nt] = *(const bf16x8*)(&Bl[cur][(wn * 64 + nt * 16 + lr) * 32 + rdoff]);

#pragma unroll
        for (int mt = 0; mt < MT; ++mt)
#pragma unroll
            for (int nt = 0; nt < 4; ++nt)
                acc[mt][nt] = mfma16(af[mt], bfr[nt], acc[mt][nt]);

        cur = (cur == 2) ? 0 : cur + 1;
        sb = (sb == 2) ? 0 : sb + 1;
    }
#undef GEMM_STAGE

#pragma unroll
    for (int mt = 0; mt < MT; ++mt) {
#pragma unroll
        for (int nt = 0; nt < 4; ++nt) {
#pragma unroll
            for (int r = 0; r < 4; ++r) {
                int row = bm + wm * (MT * 16) + mt * 16 + lh * 4 + r;
                int col = bn + wn * 64 + nt * 16 + lr;
                if (EPI == EPI_PARTIAL) {
                    ((float*)outv)[(size_t)blockIdx.y * M_ * N +
                                   (size_t)row * N + col] = acc[mt][nt][r];
                } else {
                    float v = acc[mt][nt][r] + bias[col];
                    if (EPI == EPI_RES_F32) {
                        ((float*)outv)[(size_t)row * N + col] =
                            v + res[(size_t)row * N + col];
                    } else if (EPI == EPI_GELU_BF16) {
                        // faithful: tanh(z), z = sqrt(2/pi)*0.044715*x^4
                        // g = v - v/(e^{2z}+1); z>=0, inf-safe.
                        float x4 = v * v * v * v;
                        float e = __expf(0.07135494f * x4);  // e^{2z}
                        float g = v - v / (e + 1.0f);
                        ((bf16*)outv)[(size_t)row * N + col] = (bf16)g;
                    } else {
                        ((bf16*)outv)[(size_t)row * N + col] = (bf16)v;
                    }
                }
            }
        }
    }
}

// ---------------------------------------------------------------------------
// Split-K=2 reduce: out = part0 + part1 + bias + res   (fp32, float4)
// ---------------------------------------------------------------------------
__global__ __launch_bounds__(256) void reduce2_kernel(const float* __restrict__ part,
                                                      const float* __restrict__ bias,
                                                      const float* __restrict__ res,
                                                      float* __restrict__ out) {
    const size_t MN = (size_t)M_ * C_;
    size_t i = ((size_t)blockIdx.x * 256 + threadIdx.x) * 4;
    if (i >= MN) return;
    f32x4 a = *(const f32x4*)(part + i);
    f32x4 b = *(const f32x4*)(part + MN + i);
    f32x4 r = *(const f32x4*)(res + i);
    f32x4 bi = *(const f32x4*)(bias + (int)(i % C_));
    *(f32x4*)(out + i) = a + b + r + bi;
}

// ---------------------------------------------------------------------------
// V pre-transpose: qkv V-part [t][d] per head -> vt[(b*H+h)][d=64][T=1024]
// ---------------------------------------------------------------------------
__global__ __launch_bounds__(256) void vtrans_kernel(const bf16* __restrict__ qkv,
                                                     bf16* __restrict__ vt) {
    __shared__ bf16 tl[64 * 64];
    const int tid = threadIdx.x;
    const int t0 = blockIdx.x * 64;
    const int hv = blockIdx.y;          // b*H + h
    const int b = hv / H_, h = hv % H_;
    const int src0 = h * 192 + 128;
#pragma unroll
    for (int c = 0; c < 2; ++c) {
        int i = tid + c * 256;
        int row = i >> 3, seg = i & 7;  // row = t-within-tile
        bf16x8 v = *(const bf16x8*)(qkv + (size_t)(b * T_ + t0 + row) * C3_ +
                                    src0 + seg * 8);
        *(bf16x8*)(tl + row * 64 + ((seg ^ (row & 7)) * 8)) = v;
    }
    __syncthreads();
#pragma unroll
    for (int c = 0; c < 2; ++c) {
        int i = tid + c * 256;
        int d = i >> 3, ts = i & 7;
        bf16x8 o;
#pragma unroll
        for (int j = 0; j < 8; ++j)
            o[j] = tl[(ts * 8 + j) * 64 + (d ^ (j * 8))];
        *(bf16x8*)(vt + (size_t)(hv * 64 + d) * T_ + t0 + ts * 8) = o;
    }
}

// ---------------------------------------------------------------------------
// Causal flash attention, swapped-QK^T, paired Q-tiles for load balance:
// block handles qt=p then qt=15-p -> uniform 17 chunks/block, 384 blocks,
// all co-resident (2 blocks/CU at 56KB LDS). Depth-2 prefetch (3 buffers),
// single barrier per kc + one barrier between tiles.
// ---------------------------------------------------------------------------
__global__ __launch_bounds__(256) void attn_kernel(const bf16* __restrict__ qkv,
                                                   const bf16* __restrict__ vt,
                                                   bf16* __restrict__ y) {
    const int flat = blockIdx.x;                 // 0..383
    const int pg = flat >> 3;                    // 0..47
    const int p = pg & 7;                        // pair index 0..7
    const int g = (flat & 7) * 6 + (pg >> 3);    // 0..47 = b*H+h (XCD-grouped)
    const int h = g % H_, b = g / H_, hv = g;

    const int tid = threadIdx.x, l = tid & 63, w = tid >> 6;
    const int lr = l & 15, lh = l >> 4, d0 = lh * 8;
    const int bc = h * 192;

    __shared__ bf16 Kl[3][64 * 64];
    __shared__ bf16 Vl[3][64 * 64];
    __shared__ bf16 Pl[4][16 * 64];

    const int srow = tid >> 3;
    const int ss = (tid & 7) ^ (srow & 7);
    const bf16* k0p = qkv + (size_t)(b * T_ + srow) * C3_ + bc + 64 + ss * 8;
    const bf16* k1p = k0p + (size_t)32 * C3_;
    const bf16* v0p = vt + (size_t)(hv * 64 + srow) * T_ + ss * 8;
    const bf16* v1p = v0p + (size_t)32 * T_;

#define ATTN_STAGE(buf, kc)                                                    \
    {                                                                          \
        GLOAD_LDS16(k0p + (size_t)(kc) * 64 * C3_, &Kl[buf][tid * 8]);         \
        GLOAD_LDS16(v0p + (kc) * 64, &Vl[buf][tid * 8]);                       \
        GLOAD_LDS16(k1p + (size_t)(kc) * 64 * C3_, &Kl[buf][(tid + 256) * 8]); \
        GLOAD_LDS16(v1p + (kc) * 64, &Vl[buf][(tid + 256) * 8]);               \
    }

    const float SCL = 0.125f * 1.44269504089f;  // 1/sqrt(HD) * log2(e)

    for (int sel = 0; sel < 2; ++sel) {
        const int qt = sel ? (15 - p) : p;

        const int qg = qt * 64 + w * 16 + lr;
        const bf16* qp = qkv + (size_t)(b * T_ + qg) * C3_ + bc;
        bf16x8 qf0 = *(const bf16x8*)(qp + d0);
        bf16x8 qf1 = *(const bf16x8*)(qp + 32 + d0);

        f32x4 acc_o[4] = {};
        float m_run = -1e30f, l_run = 0.f;

        ATTN_STAGE(0, 0);
        if (qt >= 1) ATTN_STAGE(1, 1);

        int cur = 0, nxt = 2;
        for (int kc = 0; kc <= qt; ++kc) {
            if (kc + 1 <= qt) {
                asm volatile("s_waitcnt vmcnt(4)" ::: "memory");
            } else {
                asm volatile("s_waitcnt vmcnt(0)" ::: "memory");
            }
            __builtin_amdgcn_s_barrier();  // the ONLY barrier per kc

            if (kc + 2 <= qt) ATTN_STAGE(nxt, kc + 2);  // issue after barrier

            const bf16* Kb = Kl[cur];
            const bf16* Vb = Vl[cur];

            // S^T = K Q^T : lane holds S[k = kc*64+nt*16+lh*4+r][q = qg]
            f32x4 st[4];
#pragma unroll
            for (int nt = 0; nt < 4; ++nt) {
                int R = nt * 16 + lr;
                const bf16* kb = Kb + R * 64;
                bf16x8 k0 = *(const bf16x8*)(kb + (lh ^ (R & 7)) * 8);
                bf16x8 k1 = *(const bf16x8*)(kb + ((4 + lh) ^ (R & 7)) * 8);
                f32x4 a = {};
                a = mfma16(k0, qf0, a);
                st[nt] = mfma16(k1, qf1, a);
            }

            // softmax in log2 domain; lane owns q-row qg, 16 k-values
            const int diag = (kc == qt);
            float pv[16], pmax = -1e30f;
#pragma unroll
            for (int nt = 0; nt < 4; ++nt)
#pragma unroll
                for (int r = 0; r < 4; ++r) {
                    float v = st[nt][r] * SCL;
                    if (diag) {
                        int kg = kc * 64 + nt * 16 + lh * 4 + r;
                        if (kg > qg) v = -1e38f;
                    }
                    pv[nt * 4 + r] = v;
                    pmax = fmaxf(pmax, v);
                }
            pmax = fmaxf(pmax, __shfl_xor(pmax, 16, 64));
            pmax = fmaxf(pmax, __shfl_xor(pmax, 32, 64));

            if (!__all(pmax - m_run <= 8.0f)) {  // defer-max (T13), THR=8
                float mnew = fmaxf(m_run, pmax);
                float sc = exp2f(m_run - mnew);
                l_run *= sc;
                m_run = mnew;
#pragma unroll
                for (int r = 0; r < 4; ++r) {
                    float sq = __shfl(sc, lh * 4 + r, 64);
#pragma unroll
                    for (int nt = 0; nt < 4; ++nt) acc_o[nt][r] *= sq;
                }
            }

            float lsum = 0.f;
#pragma unroll
            for (int i = 0; i < 16; ++i) {
                pv[i] = exp2f(pv[i] - m_run);
                lsum += pv[i];
            }
            lsum += __shfl_xor(lsum, 16, 64);
            lsum += __shfl_xor(lsum, 32, 64);
            l_run += lsum;

            // P -> Pl[q_local = lr][k], swizzled rows (per-wave buffer)
            {
                char* pw = (char*)&Pl[w][0];
                int swz = (lr & 7) << 4;
#pragma unroll
                for (int nt = 0; nt < 4; ++nt)
#pragma unroll
                    for (int rr = 0; rr < 2; ++rr) {
                        int kk = nt * 16 + lh * 4 + rr * 2;
                        bf16x2 pr = {(bf16)pv[nt * 4 + rr * 2],
                                     (bf16)pv[nt * 4 + rr * 2 + 1]};
                        *(bf16x2*)(pw + lr * 128 + ((kk * 2) ^ swz)) = pr;
                    }
            }

            // PV: a-frag = Pl rows (q_local), b-frag = Vl rows (d)
            {
                const bf16* pb = &Pl[w][0] + lr * 64;
                bf16x8 pa0 = *(const bf16x8*)(pb + (lh ^ (lr & 7)) * 8);
                bf16x8 pa1 = *(const bf16x8*)(pb + ((4 + lh) ^ (lr & 7)) * 8);
#pragma unroll
                for (int nt = 0; nt < 4; ++nt) {
                    int R = nt * 16 + lr;
                    const bf16* vb = Vb + R * 64;
                    bf16x8 v0 = *(const bf16x8*)(vb + (lh ^ (R & 7)) * 8);
                    bf16x8 v1 = *(const bf16x8*)(vb + ((4 + lh) ^ (R & 7)) * 8);
                    acc_o[nt] = mfma16(pa0, v0, acc_o[nt]);
                    acc_o[nt] = mfma16(pa1, v1, acc_o[nt]);
                }
            }

            cur = (cur == 2) ? 0 : cur + 1;
            nxt = (nxt == 2) ? 0 : nxt + 1;
        }

        float rl = 1.0f / l_run;
#pragma unroll
        for (int r = 0; r < 4; ++r) {
            float rq = __shfl(rl, lh * 4 + r, 64);
            int q = qt * 64 + w * 16 + lh * 4 + r;
#pragma unroll
            for (int nt = 0; nt < 4; ++nt)
                y[(size_t)(b * T_ + q) * C_ + h * 64 + nt * 16 + lr] =
                    (bf16)(acc_o[nt][r] * rq);
        }

        // all waves done reading tile-sel buffers before tile-(sel+1) stages
        __builtin_amdgcn_s_barrier();
    }
#undef ATTN_STAGE
}

// ---------------------------------------------------------------------------
extern "C" void kernel_launch(void* const* d_in, const int* in_sizes, int n_in,
                              void* d_out, int out_size, void* d_ws, size_t ws_size,
                              hipStream_t stream) {
    (void)in_sizes; (void)n_in; (void)out_size; (void)ws_size;
    const float* x     = (const float*)d_in[0];
    const float* ln1_s = (const float*)d_in[1];
    const float* ln1_b = (const float*)d_in[2];
    const float* Wqkv  = (const float*)d_in[3];
    const float* bqkv  = (const float*)d_in[4];
    const float* Wo    = (const float*)d_in[5];
    const float* bo    = (const float*)d_in[6];
    const float* ln2_s = (const float*)d_in[7];
    const float* ln2_b = (const float*)d_in[8];
    const float* Wfc   = (const float*)d_in[9];
    const float* bfc   = (const float*)d_in[10];
    const float* Wproj = (const float*)d_in[11];
    const float* bproj = (const float*)d_in[12];

    char* ws = (char*)d_ws;
    float* x2     = (float*)(ws);
    bf16*  vtbuf  = (bf16*)(ws);                      // aliases x2 (live: vtrans..attn)
    bf16*  fcbuf  = (bf16*)(ws + 12582912);
    bf16*  WprojT = (bf16*)(ws + 37748736);
    bf16*  lnbuf  = (bf16*)(ws + 42467328);
    float* parts  = (float*)(ws + 42467328);          // aliases lnbuf+qkv (live: proj..reduce)
    bf16*  qkv    = (bf16*)(ws + 48758784);
    bf16*  WqkvT  = (bf16*)(ws + 67633152);
    bf16*  WoT    = (bf16*)(ws + 71172096);
    bf16*  WfcT   = (bf16*)(ws + 72351744);

    tcast_all_kernel<<<dim3(6912), dim3(32, 8), 0, stream>>>(
        Wqkv, Wo, Wfc, Wproj, WqkvT, WoT, WfcT, WprojT);

    ln_kernel<<<M_, 256, 0, stream>>>(x, ln1_s, ln1_b, lnbuf);

    gemm_kernel<EPI_BF16, 4><<<dim3(576, 1), 256, 0, stream>>>(
        lnbuf, WqkvT, bqkv, nullptr, qkv, C3_, C_, 18);

    vtrans_kernel<<<dim3(T_ / 64, B_ * H_), 256, 0, stream>>>(qkv, vtbuf);

    // paired Q-tiles: 384 blocks, uniform 17 chunks each
    attn_kernel<<<dim3(384), 256, 0, stream>>>(qkv, vtbuf, lnbuf);

    // wo: N=768, K=768 -> MT=2, grid 384 (4 blocks/CU)
    gemm_kernel<EPI_RES_F32, 2><<<dim3(384, 1), 256, 0, stream>>>(
        lnbuf, WoT, bo, x, x2, C_, C_, 6);

    ln_kernel<<<M_, 256, 0, stream>>>(x2, ln2_s, ln2_b, lnbuf);

    // fc: 32 M-tiles x 24 N-tiles = 768 blocks
    gemm_kernel<EPI_GELU_BF16, 4><<<dim3(768, 1), 256, 0, stream>>>(
        lnbuf, WfcT, bfc, nullptr, fcbuf, C4_, C_, 24);

    // proj: MT=4 + split-K=2
    gemm_kernel<EPI_PARTIAL, 4><<<dim3(192, 2), 256, 0, stream>>>(
        fcbuf, WprojT, nullptr, nullptr, parts, C_, C4_, 6);

    reduce2_kernel<<<dim3((M_ * C_) / 1024), 256, 0, stream>>>(parts, bproj, x2,
                                                               (float*)d_out);
}

// Round 13
// 170.640 us; speedup vs baseline: 1.0715x; 1.0338x over previous
//
#include <hip/hip_runtime.h>
#include <hip/hip_bf16.h>
#include <math.h>

#define B_  4
#define T_  1024
#define C_  768
#define H_  12
#define HD_ 64
#define M_  (B_*T_)     // 4096 rows
#define C3_ (3*C_)      // 2304
#define C4_ (4*C_)      // 3072

typedef __bf16 bf16;
typedef bf16  bf16x2 __attribute__((ext_vector_type(2)));
typedef bf16  bf16x4 __attribute__((ext_vector_type(4)));
typedef bf16  bf16x8 __attribute__((ext_vector_type(8)));
typedef float f32x4  __attribute__((ext_vector_type(4)));

__device__ __forceinline__ f32x4 mfma16(bf16x8 a, bf16x8 b, f32x4 c) {
    return __builtin_amdgcn_mfma_f32_16x16x32_bf16(a, b, c, 0, 0, 0);
}

#define GLOAD_LDS16(g, l)                                                     \
    __builtin_amdgcn_global_load_lds(                                         \
        (const __attribute__((address_space(1))) void*)(g),                   \
        (__attribute__((address_space(3))) void*)(l), 16, 0, 0)

// ---------------------------------------------------------------------------
// Prep kernel: merged 4x weight transpose+cast AND ln1 (independent work,
// same dependency point: both feed the qkv GEMM). 256 threads flat.
//   id < 6912  : 32x32 transpose tile (range-decoded matrix)
//   id >= 6912 : ln1 row (id - 6912)
// ---------------------------------------------------------------------------
__global__ __launch_bounds__(256) void prep_kernel(
    const float* __restrict__ Wqkv, const float* __restrict__ Wo,
    const float* __restrict__ Wfc, const float* __restrict__ Wproj,
    bf16* __restrict__ WqkvT, bf16* __restrict__ WoT,
    bf16* __restrict__ WfcT, bf16* __restrict__ WprojT,
    const float* __restrict__ x, const float* __restrict__ ln1_s,
    const float* __restrict__ ln1_b, bf16* __restrict__ lnout) {
    __shared__ float tile[32][33];
    __shared__ float red[4];
    const int id = blockIdx.x;
    const int tid = threadIdx.x;

    if (id < 6912) {  // ---- transpose+cast ----
        const float* in; bf16* out; int K, N, local;
        if (id < 1728)      { in = Wqkv;  out = WqkvT;  K = 768;  N = 2304; local = id; }
        else if (id < 2304) { in = Wo;    out = WoT;    K = 768;  N = 768;  local = id - 1728; }
        else if (id < 4608) { in = Wfc;   out = WfcT;   K = 768;  N = 3072; local = id - 2304; }
        else                { in = Wproj; out = WprojT; K = 3072; N = 768;  local = id - 4608; }
        const int tn = N >> 5;
        const int n0 = (local % tn) * 32, k0 = (local / tn) * 32;
        const int tx = tid & 31, ty = tid >> 5;  // 32 x 8
#pragma unroll
        for (int i = 0; i < 32; i += 8)
            tile[ty + i][tx] = in[(size_t)(k0 + ty + i) * N + n0 + tx];
        __syncthreads();
#pragma unroll
        for (int i = 0; i < 32; i += 8)
            out[(size_t)(n0 + ty + i) * K + k0 + tx] = (bf16)tile[tx][ty + i];
    } else {  // ---- ln1 row ----
        const int row = id - 6912;
        const float* p = x + (size_t)row * C_;
        float v0 = p[tid], v1 = p[tid + 256], v2 = p[tid + 512];
        float s = v0 + v1 + v2;
#pragma unroll
        for (int m = 32; m >= 1; m >>= 1) s += __shfl_xor(s, m, 64);
        if ((tid & 63) == 0) red[tid >> 6] = s;
        __syncthreads();
        float mu = (red[0] + red[1] + red[2] + red[3]) * (1.0f / C_);
        __syncthreads();
        float d0 = v0 - mu, d1 = v1 - mu, d2 = v2 - mu;
        float q = d0 * d0 + d1 * d1 + d2 * d2;
#pragma unroll
        for (int m = 32; m >= 1; m >>= 1) q += __shfl_xor(q, m, 64);
        if ((tid & 63) == 0) red[tid >> 6] = q;
        __syncthreads();
        float var = (red[0] + red[1] + red[2] + red[3]) * (1.0f / C_);
        float rstd = rsqrtf(var + 1e-5f);
        bf16* o = lnout + (size_t)row * C_;
        o[tid]       = (bf16)(d0 * rstd * ln1_s[tid]       + ln1_b[tid]);
        o[tid + 256] = (bf16)(d1 * rstd * ln1_s[tid + 256] + ln1_b[tid + 256]);
        o[tid + 512] = (bf16)(d2 * rstd * ln1_s[tid + 512] + ln1_b[tid + 512]);
    }
}

// ---------------------------------------------------------------------------
// LayerNorm (standalone, used for ln2): fp32 in -> bf16 out, 1 block/row.
// ---------------------------------------------------------------------------
__device__ __forceinline__ float block_sum256(float v, float* red, int tid) {
#pragma unroll
    for (int m = 32; m >= 1; m >>= 1) v += __shfl_xor(v, m, 64);
    if ((tid & 63) == 0) red[tid >> 6] = v;
    __syncthreads();
    v = red[0] + red[1] + red[2] + red[3];
    __syncthreads();
    return v;
}

__global__ __launch_bounds__(256) void ln_kernel(const float* __restrict__ in,
                                                 const float* __restrict__ scale,
                                                 const float* __restrict__ bias,
                                                 bf16* __restrict__ out) {
    __shared__ float red[4];
    int row = blockIdx.x, tid = threadIdx.x;
    const float* p = in + (size_t)row * C_;
    float v0 = p[tid], v1 = p[tid + 256], v2 = p[tid + 512];
    float mu = block_sum256(v0 + v1 + v2, red, tid) * (1.0f / C_);
    float d0 = v0 - mu, d1 = v1 - mu, d2 = v2 - mu;
    float var = block_sum256(d0 * d0 + d1 * d1 + d2 * d2, red, tid) * (1.0f / C_);
    float rstd = rsqrtf(var + 1e-5f);
    bf16* o = out + (size_t)row * C_;
    o[tid]       = (bf16)(d0 * rstd * scale[tid]       + bias[tid]);
    o[tid + 256] = (bf16)(d1 * rstd * scale[tid + 256] + bias[tid + 256]);
    o[tid + 512] = (bf16)(d2 * rstd * scale[tid + 512] + bias[tid + 512]);
}

// ---------------------------------------------------------------------------
// GEMM: C[M,N] = A[M,K] * BT[N,K]^T (+epilogue). BM = MT*32, BN=128, BK=32,
// 4 waves (2x2), 3 LDS buffers, depth-2 prefetch, counted vmcnt, single
// barrier per K-step, swizzle c^((row>>1)&3). Converged (rounds 4-11).
// EPI_QKV: bf16 out, but V-region columns (col%192>=128) are written
// TRANSPOSED to vtout[(b*H+h)*64+d][t] (8B bf16x4 per lane, rows=t-contig)
// and the qkv-buffer write is skipped (only vt is consumed downstream).
// ---------------------------------------------------------------------------
enum { EPI_BF16 = 0, EPI_RES_F32 = 1, EPI_GELU_BF16 = 2, EPI_PARTIAL = 3,
       EPI_QKV = 4 };

template <int EPI, int MT>
__global__ __launch_bounds__(256) void gemm_kernel(
    const bf16* __restrict__ A, const bf16* __restrict__ BT,
    const float* __restrict__ bias, const float* __restrict__ res,
    void* __restrict__ outv, bf16* __restrict__ vtout, int N, int Ktot, int nx) {
    constexpr int BM = MT * 32;
    __shared__ bf16 Al[3][BM * 32];
    __shared__ bf16 Bl[3][128 * 32];
    const int tid = threadIdx.x;
    const int l = tid & 63, w = tid >> 6;
    const int wm = w >> 1, wn = w & 1;
    // bijective XCD-chunked swizzle (gridDim.x divisible by 8)
    const int cpx = gridDim.x >> 3;
    const int wg = (blockIdx.x & 7) * cpx + (blockIdx.x >> 3);
    const int bm = (wg / nx) * BM, bn = (wg % nx) * 128;
    const int Kper = Ktot / gridDim.y;
    const int k0 = blockIdx.y * Kper;
    const int lr = l & 15, lh = l >> 4;

    const int srow = tid >> 2;
    const int scol = ((tid & 3) ^ ((srow >> 1) & 3)) * 8;
    const bf16* gA = A + (size_t)(bm + srow) * Ktot + k0 + scol;
    const bf16* gB = BT + (size_t)(bn + srow) * Ktot + k0 + scol;

#define GEMM_STAGE(buf, koff)                                                  \
    {                                                                          \
        GLOAD_LDS16(gA + (koff), &Al[buf][tid * 8]);                           \
        if (MT == 4)                                                           \
            GLOAD_LDS16(gA + (size_t)64 * Ktot + (koff),                       \
                        &Al[buf][(tid + 256) * 8]);                            \
        GLOAD_LDS16(gB + (koff), &Bl[buf][tid * 8]);                           \
        GLOAD_LDS16(gB + (size_t)64 * Ktot + (koff),                           \
                    &Bl[buf][(tid + 256) * 8]);                                \
    }

    const int rdoff = (lh ^ ((lr >> 1) & 3)) * 8;

    f32x4 acc[MT][4] = {};
    const int nk = Kper >> 5;

    GEMM_STAGE(0, 0);
    GEMM_STAGE(1, 32);

    int cur = 0, sb = 2;
    for (int t = 0; t < nk; ++t) {
        if (t + 1 < nk) {
            if (MT == 4) asm volatile("s_waitcnt vmcnt(4)" ::: "memory");
            else         asm volatile("s_waitcnt vmcnt(3)" ::: "memory");
        } else {
            asm volatile("s_waitcnt vmcnt(0)" ::: "memory");
        }
        __builtin_amdgcn_s_barrier();  // the ONLY barrier per K-step

        if (t + 2 < nk) GEMM_STAGE(sb, (t + 2) * 32);  // issue after barrier

        bf16x8 af[MT], bfr[4];
#pragma unroll
        for (int mt = 0; mt < MT; ++mt)
            af[mt] = *(const bf16x8*)(&Al[cur][(wm * (MT * 16) + mt * 16 + lr) * 32 + rdoff]);
#pragma unroll
        for (int nt = 0; nt < 4; ++nt)
            bfr[nt] = *(const bf16x8*)(&Bl[cur][(wn * 64 + nt * 16 + lr) * 32 + rdoff]);

#pragma unroll
        for (int mt = 0; mt < MT; ++mt)
#pragma unroll
            for (int nt = 0; nt < 4; ++nt)
                acc[mt][nt] = mfma16(af[mt], bfr[nt], acc[mt][nt]);

        cur = (cur == 2) ? 0 : cur + 1;
        sb = (sb == 2) ? 0 : sb + 1;
    }
#undef GEMM_STAGE

#pragma unroll
    for (int mt = 0; mt < MT; ++mt) {
#pragma unroll
        for (int nt = 0; nt < 4; ++nt) {
            const int row0 = bm + wm * (MT * 16) + mt * 16 + lh * 4;
            const int col = bn + wn * 64 + nt * 16 + lr;
            if (EPI == EPI_QKV && (col % 192) >= 128) {
                // V fragment: transposed write to vt, skip qkv write.
                // (fragment is uniformly in/out: V regions are 64-aligned,
                //  fragments 16-aligned; rows r are t-contiguous, same b.)
                const int hh = col / 192, d = (col % 192) - 128;
                const int bb = row0 >> 10, t0 = row0 & 1023;
                bf16x4 tv;
#pragma unroll
                for (int r = 0; r < 4; ++r)
                    tv[r] = (bf16)(acc[mt][nt][r] + bias[col]);
                *(bf16x4*)(vtout + ((size_t)(bb * H_ + hh) * 64 + d) * 1024 + t0) = tv;
                continue;
            }
#pragma unroll
            for (int r = 0; r < 4; ++r) {
                int row = row0 + r;
                if (EPI == EPI_PARTIAL) {
                    ((float*)outv)[(size_t)blockIdx.y * M_ * N +
                                   (size_t)row * N + col] = acc[mt][nt][r];
                } else {
                    float v = acc[mt][nt][r] + bias[col];
                    if (EPI == EPI_RES_F32) {
                        ((float*)outv)[(size_t)row * N + col] =
                            v + res[(size_t)row * N + col];
                    } else if (EPI == EPI_GELU_BF16) {
                        // faithful: tanh(z), z = sqrt(2/pi)*0.044715*x^4
                        // g = v - v/(e^{2z}+1); z>=0, inf-safe.
                        float x4 = v * v * v * v;
                        float e = __expf(0.07135494f * x4);  // e^{2z}
                        float g = v - v / (e + 1.0f);
                        ((bf16*)outv)[(size_t)row * N + col] = (bf16)g;
                    } else {  // EPI_BF16 or EPI_QKV (Q/K columns)
                        ((bf16*)outv)[(size_t)row * N + col] = (bf16)v;
                    }
                }
            }
        }
    }
}

// ---------------------------------------------------------------------------
// Split-K=2 reduce: out = part0 + part1 + bias + res   (fp32, float4)
// ---------------------------------------------------------------------------
__global__ __launch_bounds__(256) void reduce2_kernel(const float* __restrict__ part,
                                                      const float* __restrict__ bias,
                                                      const float* __restrict__ res,
                                                      float* __restrict__ out) {
    const size_t MN = (size_t)M_ * C_;
    size_t i = ((size_t)blockIdx.x * 256 + threadIdx.x) * 4;
    if (i >= MN) return;
    f32x4 a = *(const f32x4*)(part + i);
    f32x4 b = *(const f32x4*)(part + MN + i);
    f32x4 r = *(const f32x4*)(res + i);
    f32x4 bi = *(const f32x4*)(bias + (int)(i % C_));
    *(f32x4*)(out + i) = a + b + r + bi;
}

// ---------------------------------------------------------------------------
// Causal flash attention, swapped-QK^T, paired Q-tiles for load balance:
// block handles qt=p then qt=15-p -> uniform 17 chunks/block, 384 blocks,
// all co-resident. Depth-2 prefetch (3 buffers), single barrier per kc.
// ---------------------------------------------------------------------------
__global__ __launch_bounds__(256) void attn_kernel(const bf16* __restrict__ qkv,
                                                   const bf16* __restrict__ vt,
                                                   bf16* __restrict__ y) {
    const int flat = blockIdx.x;                 // 0..383
    const int pg = flat >> 3;                    // 0..47
    const int p = pg & 7;                        // pair index 0..7
    const int g = (flat & 7) * 6 + (pg >> 3);    // 0..47 = b*H+h (XCD-grouped)
    const int h = g % H_, b = g / H_, hv = g;

    const int tid = threadIdx.x, l = tid & 63, w = tid >> 6;
    const int lr = l & 15, lh = l >> 4, d0 = lh * 8;
    const int bc = h * 192;

    __shared__ bf16 Kl[3][64 * 64];
    __shared__ bf16 Vl[3][64 * 64];
    __shared__ bf16 Pl[4][16 * 64];

    const int srow = tid >> 3;
    const int ss = (tid & 7) ^ (srow & 7);
    const bf16* k0p = qkv + (size_t)(b * T_ + srow) * C3_ + bc + 64 + ss * 8;
    const bf16* k1p = k0p + (size_t)32 * C3_;
    const bf16* v0p = vt + (size_t)(hv * 64 + srow) * T_ + ss * 8;
    const bf16* v1p = v0p + (size_t)32 * T_;

#define ATTN_STAGE(buf, kc)                                                    \
    {                                                                          \
        GLOAD_LDS16(k0p + (size_t)(kc) * 64 * C3_, &Kl[buf][tid * 8]);         \
        GLOAD_LDS16(v0p + (kc) * 64, &Vl[buf][tid * 8]);                       \
        GLOAD_LDS16(k1p + (size_t)(kc) * 64 * C3_, &Kl[buf][(tid + 256) * 8]); \
        GLOAD_LDS16(v1p + (kc) * 64, &Vl[buf][(tid + 256) * 8]);               \
    }

    const float SCL = 0.125f * 1.44269504089f;  // 1/sqrt(HD) * log2(e)

    for (int sel = 0; sel < 2; ++sel) {
        const int qt = sel ? (15 - p) : p;

        const int qg = qt * 64 + w * 16 + lr;
        const bf16* qp = qkv + (size_t)(b * T_ + qg) * C3_ + bc;
        bf16x8 qf0 = *(const bf16x8*)(qp + d0);
        bf16x8 qf1 = *(const bf16x8*)(qp + 32 + d0);

        f32x4 acc_o[4] = {};
        float m_run = -1e30f, l_run = 0.f;

        ATTN_STAGE(0, 0);
        if (qt >= 1) ATTN_STAGE(1, 1);

        int cur = 0, nxt = 2;
        for (int kc = 0; kc <= qt; ++kc) {
            if (kc + 1 <= qt) {
                asm volatile("s_waitcnt vmcnt(4)" ::: "memory");
            } else {
                asm volatile("s_waitcnt vmcnt(0)" ::: "memory");
            }
            __builtin_amdgcn_s_barrier();  // the ONLY barrier per kc

            if (kc + 2 <= qt) ATTN_STAGE(nxt, kc + 2);  // issue after barrier

            const bf16* Kb = Kl[cur];
            const bf16* Vb = Vl[cur];

            // S^T = K Q^T : lane holds S[k = kc*64+nt*16+lh*4+r][q = qg]
            f32x4 st[4];
#pragma unroll
            for (int nt = 0; nt < 4; ++nt) {
                int R = nt * 16 + lr;
                const bf16* kb = Kb + R * 64;
                bf16x8 k0 = *(const bf16x8*)(kb + (lh ^ (R & 7)) * 8);
                bf16x8 k1 = *(const bf16x8*)(kb + ((4 + lh) ^ (R & 7)) * 8);
                f32x4 a = {};
                a = mfma16(k0, qf0, a);
                st[nt] = mfma16(k1, qf1, a);
            }

            // softmax in log2 domain; lane owns q-row qg, 16 k-values
            const int diag = (kc == qt);
            float pv[16], pmax = -1e30f;
#pragma unroll
            for (int nt = 0; nt < 4; ++nt)
#pragma unroll
                for (int r = 0; r < 4; ++r) {
                    float v = st[nt][r] * SCL;
                    if (diag) {
                        int kg = kc * 64 + nt * 16 + lh * 4 + r;
                        if (kg > qg) v = -1e38f;
                    }
                    pv[nt * 4 + r] = v;
                    pmax = fmaxf(pmax, v);
                }
            pmax = fmaxf(pmax, __shfl_xor(pmax, 16, 64));
            pmax = fmaxf(pmax, __shfl_xor(pmax, 32, 64));

            if (!__all(pmax - m_run <= 8.0f)) {  // defer-max (T13), THR=8
                float mnew = fmaxf(m_run, pmax);
                float sc = exp2f(m_run - mnew);
                l_run *= sc;
                m_run = mnew;
#pragma unroll
                for (int r = 0; r < 4; ++r) {
                    float sq = __shfl(sc, lh * 4 + r, 64);
#pragma unroll
                    for (int nt = 0; nt < 4; ++nt) acc_o[nt][r] *= sq;
                }
            }

            float lsum = 0.f;
#pragma unroll
            for (int i = 0; i < 16; ++i) {
                pv[i] = exp2f(pv[i] - m_run);
                lsum += pv[i];
            }
            lsum += __shfl_xor(lsum, 16, 64);
            lsum += __shfl_xor(lsum, 32, 64);
            l_run += lsum;

            // P -> Pl[q_local = lr][k], swizzled rows (per-wave buffer)
            {
                char* pw = (char*)&Pl[w][0];
                int swz = (lr & 7) << 4;
#pragma unroll
                for (int nt = 0; nt < 4; ++nt)
#pragma unroll
                    for (int rr = 0; rr < 2; ++rr) {
                        int kk = nt * 16 + lh * 4 + rr * 2;
                        bf16x2 pr = {(bf16)pv[nt * 4 + rr * 2],
                                     (bf16)pv[nt * 4 + rr * 2 + 1]};
                        *(bf16x2*)(pw + lr * 128 + ((kk * 2) ^ swz)) = pr;
                    }
            }

            // PV: a-frag = Pl rows (q_local), b-frag = Vl rows (d)
            {
                const bf16* pb = &Pl[w][0] + lr * 64;
                bf16x8 pa0 = *(const bf16x8*)(pb + (lh ^ (lr & 7)) * 8);
                bf16x8 pa1 = *(const bf16x8*)(pb + ((4 + lh) ^ (lr & 7)) * 8);
#pragma unroll
                for (int nt = 0; nt < 4; ++nt) {
                    int R = nt * 16 + lr;
                    const bf16* vb = Vb + R * 64;
                    bf16x8 v0 = *(const bf16x8*)(vb + (lh ^ (R & 7)) * 8);
                    bf16x8 v1 = *(const bf16x8*)(vb + ((4 + lh) ^ (R & 7)) * 8);
                    acc_o[nt] = mfma16(pa0, v0, acc_o[nt]);
                    acc_o[nt] = mfma16(pa1, v1, acc_o[nt]);
                }
            }

            cur = (cur == 2) ? 0 : cur + 1;
            nxt = (nxt == 2) ? 0 : nxt + 1;
        }

        float rl = 1.0f / l_run;
#pragma unroll
        for (int r = 0; r < 4; ++r) {
            float rq = __shfl(rl, lh * 4 + r, 64);
            int q = qt * 64 + w * 16 + lh * 4 + r;
#pragma unroll
            for (int nt = 0; nt < 4; ++nt)
                y[(size_t)(b * T_ + q) * C_ + h * 64 + nt * 16 + lr] =
                    (bf16)(acc_o[nt][r] * rq);
        }

        // all waves done reading tile-sel buffers before tile-(sel+1) stages
        __builtin_amdgcn_s_barrier();
    }
#undef ATTN_STAGE
}

// ---------------------------------------------------------------------------
extern "C" void kernel_launch(void* const* d_in, const int* in_sizes, int n_in,
                              void* d_out, int out_size, void* d_ws, size_t ws_size,
                              hipStream_t stream) {
    (void)in_sizes; (void)n_in; (void)out_size; (void)ws_size;
    const float* x     = (const float*)d_in[0];
    const float* ln1_s = (const float*)d_in[1];
    const float* ln1_b = (const float*)d_in[2];
    const float* Wqkv  = (const float*)d_in[3];
    const float* bqkv  = (const float*)d_in[4];
    const float* Wo    = (const float*)d_in[5];
    const float* bo    = (const float*)d_in[6];
    const float* ln2_s = (const float*)d_in[7];
    const float* ln2_b = (const float*)d_in[8];
    const float* Wfc   = (const float*)d_in[9];
    const float* bfc   = (const float*)d_in[10];
    const float* Wproj = (const float*)d_in[11];
    const float* bproj = (const float*)d_in[12];

    char* ws = (char*)d_ws;
    float* x2     = (float*)(ws);
    bf16*  vtbuf  = (bf16*)(ws);                      // aliases x2 (live: qkv-gemm..attn)
    bf16*  fcbuf  = (bf16*)(ws + 12582912);
    bf16*  WprojT = (bf16*)(ws + 37748736);
    bf16*  lnbuf  = (bf16*)(ws + 42467328);
    float* parts  = (float*)(ws + 42467328);          // aliases lnbuf+qkv (live: proj..reduce)
    bf16*  qkv    = (bf16*)(ws + 48758784);
    bf16*  WqkvT  = (bf16*)(ws + 67633152);
    bf16*  WoT    = (bf16*)(ws + 71172096);
    bf16*  WfcT   = (bf16*)(ws + 72351744);

    // 1: weights transpose+cast + ln1 (merged)
    prep_kernel<<<dim3(6912 + 4096), 256, 0, stream>>>(
        Wqkv, Wo, Wfc, Wproj, WqkvT, WoT, WfcT, WprojT, x, ln1_s, ln1_b, lnbuf);

    // 2: qkv GEMM; V third written transposed to vtbuf in the epilogue
    gemm_kernel<EPI_QKV, 4><<<dim3(576, 1), 256, 0, stream>>>(
        lnbuf, WqkvT, bqkv, nullptr, qkv, vtbuf, C3_, C_, 18);

    // 3: attention (paired Q-tiles, 384 uniform blocks)
    attn_kernel<<<dim3(384), 256, 0, stream>>>(qkv, vtbuf, lnbuf);

    // 4: wo (N=768, K=768 -> MT=2, grid 384)
    gemm_kernel<EPI_RES_F32, 2><<<dim3(384, 1), 256, 0, stream>>>(
        lnbuf, WoT, bo, x, x2, nullptr, C_, C_, 6);

    // 5: ln2
    ln_kernel<<<M_, 256, 0, stream>>>(x2, ln2_s, ln2_b, lnbuf);

    // 6: fc (768 blocks)
    gemm_kernel<EPI_GELU_BF16, 4><<<dim3(768, 1), 256, 0, stream>>>(
        lnbuf, WfcT, bfc, nullptr, fcbuf, nullptr, C4_, C_, 24);

    // 7: proj (MT=4 + split-K=2)
    gemm_kernel<EPI_PARTIAL, 4><<<dim3(192, 2), 256, 0, stream>>>(
        fcbuf, WprojT, nullptr, nullptr, parts, nullptr, C_, C4_, 6);

    // 8: reduce (bias + residual fused)
    reduce2_kernel<<<dim3((M_ * C_) / 1024), 256, 0, stream>>>(parts, bproj, x2,
                                                               (float*)d_out);
}